// Round 1
// baseline (771.241 us; speedup 1.0000x reference)
//
#include <hip/hip_runtime.h>
#include <math.h>

// RowLSTM: x(16,64,64,64) fp32, Wi(512,64,1,3), bi(512), Wh(512,128), bh(512)
// out: (16,128,64,64) fp32
//
// Phase 1: i2h = conv1d_w(x, Wi) + (bi+bh), stored in ws as [b][h][wt][d][8] (wt = w/8)
// Phase 2: per-(b, 8-col tile) workgroup runs the full H=64 recurrence locally.
//          gates[d,w] = i2h[d,w] + sum_c WhT[c][d]*h[c][w]
//
// ws layout (floats): [0, 65536): WhT (128 x 512), [65536, 65536+33554432): i2h
// ws bytes needed: ~128.3 MiB

#define BB 16
#define CC 64
#define HH 64
#define WW 64
#define HID 128
#define GG 512  // 4*HID
#define KW 3

// ---------------- K0: transpose Wh (512x128) -> WhT (128x512) ----------------
__global__ __launch_bounds__(256) void k_transpose_wh(const float* __restrict__ Wh,
                                                      float* __restrict__ WhT) {
    int n = blockIdx.x * 256 + threadIdx.x;  // n = c*512 + d
    int c = n >> 9;
    int d = n & 511;
    WhT[n] = Wh[d * HID + c];
}

// ---------------- K1: i2h conv ----------------
// grid: (B*H) wgs of 256 threads. Each wg computes all 512x64 outputs for one (b,h).
// thread: dgrp = t>>2 (8 gate rows), cgrp = t&3 (16 cols). 128 outputs/thread.
__global__ __launch_bounds__(256) void k_conv(const float* __restrict__ x,
                                              const float* __restrict__ Wi,
                                              const float* __restrict__ bi,
                                              const float* __restrict__ bh,
                                              float* __restrict__ i2h) {
    __shared__ float xs[CC][68];  // stride 68 floats: 16B-aligned rows
    const int b = blockIdx.x >> 6;
    const int h = blockIdx.x & 63;
    const int t = threadIdx.x;

    // stage x[b, :, h, :] (64x64 fp32 = 16 KB), coalesced float4
    #pragma unroll
    for (int i = 0; i < 4; ++i) {
        int idx = t + i * 256;             // 0..1023
        int c = idx >> 4;
        int w4 = (idx & 15) << 2;
        const float4 v = *(const float4*)&x[(((size_t)b * CC + c) * HH + h) * WW + w4];
        *(float4*)&xs[c][w4] = v;
    }
    __syncthreads();

    const int dgrp = t >> 2;
    const int cgrp = t & 3;
    const int d0 = dgrp * 8;
    const int w0 = cgrp * 16;

    float acc[8][16];
    #pragma unroll
    for (int i = 0; i < 8; ++i) {
        float bias = bi[d0 + i] + bh[d0 + i];
        #pragma unroll
        for (int j = 0; j < 16; ++j) acc[i][j] = bias;
    }

    #pragma unroll 1
    for (int c = 0; c < CC; ++c) {
        float xw[18];  // xw[j] = x[c][w0 - 1 + j], zero-padded at edges
        xw[0] = (w0 == 0) ? 0.f : xs[c][w0 - 1];
        #pragma unroll
        for (int j = 0; j < 16; ++j) xw[j + 1] = xs[c][w0 + j];
        xw[17] = (w0 + 16 == WW) ? 0.f : xs[c][w0 + 16];

        #pragma unroll
        for (int i = 0; i < 8; ++i) {
            const float* wr = &Wi[(size_t)(d0 + i) * (CC * KW) + c * KW];
            const float wv0 = wr[0];
            const float wv1 = wr[1];
            const float wv2 = wr[2];
            #pragma unroll
            for (int j = 0; j < 16; ++j)
                acc[i][j] += wv0 * xw[j] + wv1 * xw[j + 1] + wv2 * xw[j + 2];
        }
    }

    // write out: layout [b][h][wt][d][8];  this thread covers wt0 = 2*cgrp and wt0+1
    const int wt0 = w0 >> 3;
    size_t base = (((size_t)b * HH + h) * 8 + wt0) * (GG * 8) + (size_t)d0 * 8;
    #pragma unroll
    for (int i = 0; i < 8; ++i) {
        float4 a0 = {acc[i][0], acc[i][1], acc[i][2], acc[i][3]};
        float4 a1 = {acc[i][4], acc[i][5], acc[i][6], acc[i][7]};
        float4 b0 = {acc[i][8], acc[i][9], acc[i][10], acc[i][11]};
        float4 b1 = {acc[i][12], acc[i][13], acc[i][14], acc[i][15]};
        *(float4*)&i2h[base + (size_t)i * 8 + 0] = a0;
        *(float4*)&i2h[base + (size_t)i * 8 + 4] = a1;
        *(float4*)&i2h[base + (size_t)(GG * 8) + i * 8 + 0] = b0;
        *(float4*)&i2h[base + (size_t)(GG * 8) + i * 8 + 4] = b1;
    }
}

// ---------------- K2: recurrent scan over H ----------------
// grid: 128 wgs = (b, wt) with wt = 8-col tile. 512 threads: thread t = gate row d.
__global__ __launch_bounds__(512) void k_lstm(const float* __restrict__ i2h,
                                              const float* __restrict__ WhT,
                                              float* __restrict__ out) {
    __shared__ float hs[HID][8];     // h state, row-aligned for float4 broadcast reads
    __shared__ float gs[GG][9];      // gate exchange, pad 9 to spread banks
    const int b = blockIdx.x >> 3;
    const int wt = blockIdx.x & 7;
    const int t = threadIdx.x;

    float cellc[8];
    if (t < HID) {
        #pragma unroll
        for (int w = 0; w < 8; ++w) { hs[t][w] = 0.f; cellc[w] = 0.f; }
    }
    __syncthreads();

    for (int hr = 0; hr < HH; ++hr) {
        // load this row's i2h gates (already biased): contiguous 32B per lane
        const size_t gbase = (((size_t)b * HH + hr) * 8 + wt) * (GG * 8) + (size_t)t * 8;
        const float4 g0v = *(const float4*)&i2h[gbase];
        const float4 g1v = *(const float4*)&i2h[gbase + 4];
        float g[8] = {g0v.x, g0v.y, g0v.z, g0v.w, g1v.x, g1v.y, g1v.z, g1v.w};

        // g[w] += sum_c WhT[c][t] * h[c][w]
        #pragma unroll 4
        for (int c = 0; c < HID; ++c) {
            const float wh = WhT[(size_t)c * GG + t];  // coalesced across lanes
            const float4 h0 = *(const float4*)&hs[c][0];  // broadcast
            const float4 h1 = *(const float4*)&hs[c][4];
            g[0] += wh * h0.x; g[1] += wh * h0.y; g[2] += wh * h0.z; g[3] += wh * h0.w;
            g[4] += wh * h1.x; g[5] += wh * h1.y; g[6] += wh * h1.z; g[7] += wh * h1.w;
        }

        #pragma unroll
        for (int w = 0; w < 8; ++w) gs[t][w] = g[w];
        __syncthreads();

        if (t < HID) {
            float hv[8];
            #pragma unroll
            for (int w = 0; w < 8; ++w) {
                const float ig = gs[t][w];
                const float fg = gs[t + HID][w];
                const float og = gs[t + 2 * HID][w];
                const float gg = gs[t + 3 * HID][w];
                const float si = 1.f / (1.f + __expf(-ig));
                const float sf = 1.f / (1.f + __expf(-fg));
                const float so = 1.f / (1.f + __expf(-og));
                const float tg = tanhf(gg);
                cellc[w] = sf * cellc[w] + si * tg;
                hv[w] = so * tanhf(cellc[w]);
                hs[t][w] = hv[w];
            }
            // out[b][t][hr][wt*8 + w]
            const size_t obase = (((size_t)b * HID + t) * HH + hr) * WW + (size_t)wt * 8;
            float4 o0 = {hv[0], hv[1], hv[2], hv[3]};
            float4 o1 = {hv[4], hv[5], hv[6], hv[7]};
            *(float4*)&out[obase] = o0;
            *(float4*)&out[obase + 4] = o1;
        }
        __syncthreads();
    }
}

extern "C" void kernel_launch(void* const* d_in, const int* in_sizes, int n_in,
                              void* d_out, int out_size, void* d_ws, size_t ws_size,
                              hipStream_t stream) {
    const float* x  = (const float*)d_in[0];
    const float* Wi = (const float*)d_in[1];
    const float* bi = (const float*)d_in[2];
    const float* Wh = (const float*)d_in[3];
    const float* bh = (const float*)d_in[4];
    float* out = (float*)d_out;
    float* ws  = (float*)d_ws;

    float* WhT = ws;                 // 65536 floats
    float* i2h = ws + 65536;         // 33554432 floats (134.2 MB)

    hipLaunchKernelGGL(k_transpose_wh, dim3(128 * 512 / 256), dim3(256), 0, stream, Wh, WhT);
    hipLaunchKernelGGL(k_conv, dim3(BB * HH), dim3(256), 0, stream, x, Wi, bi, bh, i2h);
    hipLaunchKernelGGL(k_lstm, dim3(BB * (WW / 8)), dim3(512), 0, stream, i2h, WhT, out);
}